// Round 2
// baseline (16759.064 us; speedup 1.0000x reference)
//
#include <hip/hip_runtime.h>
#include <hip/hip_bf16.h>
#include <math.h>
#include <stdint.h>

#define BB 32
#define TT 512
#define II 512
#define HH 512
#define G4 (4 * HH)      // 2048
#define MM (TT * BB)     // 16384 rows of gx per direction
#define NWG_DIR 128      // workgroups per direction in recurrent kernel
#define BH (BB * HH)     // 16384

typedef __hip_bfloat16 bf16;

__device__ __forceinline__ float bf2f(bf16 v) { return __bfloat162float(v); }
__device__ __forceinline__ bf16  f2bf(float v) { return __float2bfloat16(v); }

// ---------------------------------------------------------------------------
// Phase 1: gx[dl][m][n] = x_row(m) . w_ih[dir][n][:] + b_ih[n] + b_hh[n]
//   dir = dir0 + blockIdx.z (dl = blockIdx.z is the local buffer index)
//   m = t*32 + b  (t-major so phase 2 reads [b][g] contiguously per step)
//   n = gate*512 + j   (PyTorch gate order i,f,g,o)
// fp32 LDS-tiled GEMM, 64x64 tile, 256 threads, 4x4 micro-tile, K-tile 16.
// ---------------------------------------------------------------------------
__global__ __launch_bounds__(256) void proj_kernel(
    const float* __restrict__ x,
    const float* __restrict__ w_f, const float* __restrict__ w_r,
    const float* __restrict__ bi_f, const float* __restrict__ bh_f,
    const float* __restrict__ bi_r, const float* __restrict__ bh_r,
    bf16* __restrict__ gx, int dir0)
{
    const int dl  = blockIdx.z;
    const int dir = dir0 + dl;
    const int m0 = blockIdx.x * 64;
    const int n0 = blockIdx.y * 64;
    const float* __restrict__ w  = dir ? w_r  : w_f;
    const float* __restrict__ bi = dir ? bi_r : bi_f;
    const float* __restrict__ bh = dir ? bh_r : bh_f;

    __shared__ __align__(16) float xs[16][68];  // [k][m], +4 pad
    __shared__ __align__(16) float ws[16][68];  // [k][n], +4 pad

    const int tid = threadIdx.x;
    const int tx = tid & 15, ty = tid >> 4;
    const int lm = tid >> 2, kq = tid & 3;

    const int ml = m0 + lm;                         // gx row this thread stages
    const float* xrow = x + ((size_t)(ml & 31) * TT + (size_t)(ml >> 5)) * II;
    const float* wrow = w + (size_t)(n0 + lm) * II;

    float acc[4][4];
#pragma unroll
    for (int i = 0; i < 4; ++i)
#pragma unroll
        for (int j = 0; j < 4; ++j) acc[i][j] = 0.f;

    for (int k0 = 0; k0 < II; k0 += 16) {
        const float4 xv = *(const float4*)(xrow + k0 + kq * 4);
        const float4 wv = *(const float4*)(wrow + k0 + kq * 4);
        __syncthreads();   // previous tile fully consumed
        xs[kq * 4 + 0][lm] = xv.x; xs[kq * 4 + 1][lm] = xv.y;
        xs[kq * 4 + 2][lm] = xv.z; xs[kq * 4 + 3][lm] = xv.w;
        ws[kq * 4 + 0][lm] = wv.x; ws[kq * 4 + 1][lm] = wv.y;
        ws[kq * 4 + 2][lm] = wv.z; ws[kq * 4 + 3][lm] = wv.w;
        __syncthreads();
#pragma unroll
        for (int kk = 0; kk < 16; ++kk) {
            const float4 a = *(const float4*)&xs[kk][ty * 4];
            const float4 b = *(const float4*)&ws[kk][tx * 4];
            acc[0][0] += a.x * b.x; acc[0][1] += a.x * b.y; acc[0][2] += a.x * b.z; acc[0][3] += a.x * b.w;
            acc[1][0] += a.y * b.x; acc[1][1] += a.y * b.y; acc[1][2] += a.y * b.z; acc[1][3] += a.y * b.w;
            acc[2][0] += a.z * b.x; acc[2][1] += a.z * b.y; acc[2][2] += a.z * b.z; acc[2][3] += a.z * b.w;
            acc[3][0] += a.w * b.x; acc[3][1] += a.w * b.y; acc[3][2] += a.w * b.z; acc[3][3] += a.w * b.w;
        }
    }

    float bias[4];
#pragma unroll
    for (int ni = 0; ni < 4; ++ni) {
        const int n = n0 + tx * 4 + ni;
        bias[ni] = bi[n] + bh[n];
    }
    const size_t gbase = (size_t)dl * MM * G4;
#pragma unroll
    for (int mi = 0; mi < 4; ++mi) {
        const int m = m0 + ty * 4 + mi;
        bf16* gr = gx + gbase + (size_t)m * G4 + (n0 + tx * 4);
#pragma unroll
        for (int ni = 0; ni < 4; ++ni) gr[ni] = f2bf(acc[mi][ni] + bias[ni]);
    }
}

// ---------------------------------------------------------------------------
// Phase 2: persistent bidirectional LSTM recurrence, PLAIN launch.
// ndir*128 WGs x 256 threads, 1 block/CU (54 KB LDS) -> all co-resident.
// WG (dl, wg) owns h-columns j0..j0+3 of direction dir0+dl. w_hh rows staged
// in LDS (bf16) once; h broadcast per step via double-buffered global bf16
// buffer; c in registers; per-direction monotonic-counter device barrier.
// ---------------------------------------------------------------------------
__global__ __launch_bounds__(256) void lstm_rec_kernel(
    const bf16* __restrict__ gx,
    const float* __restrict__ h0, const float* __restrict__ c0,
    const float* __restrict__ whh_f, const float* __restrict__ whh_r,
    float* __restrict__ dout,
    bf16* __restrict__ h_buf,          // [ndir][2 slots][B*H]
    unsigned int* __restrict__ bars,   // per-local-dir counters, 256B apart
    int dir0)
{
    const int wgid = blockIdx.x;
    const int dl  = wgid >> 7;
    const int dir = dir0 + dl;
    const int wg  = wgid & 127;
    const int j0  = wg * 4;
    const float* __restrict__ whh = dir ? whh_r : whh_f;
    unsigned int* bar = bars + dl * 64;

    __shared__ __align__(16) bf16 w_s[16][520];   // [gate*4+col][k], pad breaks 512-stride
    __shared__ __align__(16) bf16 h_s[32][520];   // [b][k]
    __shared__ float ps[32][4][4][2];             // [b][col][gate][khalf]

    const int tid = threadIdx.x;

    // Stage this WG's 16 w_hh rows once (row r = gate*4+col -> global gate*512+j0+col).
    for (int q = 0; q < 32; ++q) {
        const int f = q * 256 + tid;              // 0..8191
        const int r = f >> 9, k = f & 511;
        const int grow = (r >> 2) * HH + j0 + (r & 3);
        w_s[r][k] = f2bf(whh[(size_t)grow * HH + k]);
    }

    const int b_t = tid >> 3;                     // compute role: batch row
    const int ct  = (tid >> 1) & 3;               // column within WG
    const int kh  = tid & 1;                      // K half
    const int bu  = tid >> 2, cu = tid & 3;       // update role (tid<128)

    float c_state = 0.f;
    if (tid < 128) c_state = c0[(size_t)dir * BH + (size_t)bu * HH + j0 + cu];

    bf16* hslot = h_buf + (size_t)dl * 2 * BH;
    const bf16* gxd = gx + (size_t)dl * MM * G4;

    for (int s = 0; s < TT; ++s) {
        // ---- stage h_state[s] into LDS ----
        if (s == 0) {
            for (int q = 0; q < 64; ++q) {
                const int f = q * 256 + tid;      // 0..16383 = b*512+k
                h_s[f >> 9][f & 511] = f2bf(h0[(size_t)dir * BH + f]);
            }
        } else {
            const uint32_t* src = (const uint32_t*)(hslot + (size_t)(s & 1) * BH);
            for (int q = 0; q < 32; ++q) {
                const int pf = q * 256 + tid;     // 0..8191 uint pairs
                const uint32_t v = src[pf];
                *(uint32_t*)&h_s[pf >> 8][(pf & 255) * 2] = v;
            }
        }
        __syncthreads();

        // ---- partial dot products: thread = (b, col, khalf), 4 gates ----
        float a0 = 0.f, a1 = 0.f, a2 = 0.f, a3 = 0.f;
        {
            const uint32_t* hr = (const uint32_t*)&h_s[b_t][kh * 256];
            const uint32_t* w0 = (const uint32_t*)&w_s[0 * 4 + ct][kh * 256];
            const uint32_t* w1 = (const uint32_t*)&w_s[1 * 4 + ct][kh * 256];
            const uint32_t* w2 = (const uint32_t*)&w_s[2 * 4 + ct][kh * 256];
            const uint32_t* w3 = (const uint32_t*)&w_s[3 * 4 + ct][kh * 256];
#pragma unroll 8
            for (int kk = 0; kk < 128; ++kk) {
                const uint32_t hv = hr[kk];
                const float hlo = __uint_as_float(hv << 16);
                const float hhi = __uint_as_float(hv & 0xffff0000u);
                uint32_t u;
                u = w0[kk]; a0 += hlo * __uint_as_float(u << 16); a0 += hhi * __uint_as_float(u & 0xffff0000u);
                u = w1[kk]; a1 += hlo * __uint_as_float(u << 16); a1 += hhi * __uint_as_float(u & 0xffff0000u);
                u = w2[kk]; a2 += hlo * __uint_as_float(u << 16); a2 += hhi * __uint_as_float(u & 0xffff0000u);
                u = w3[kk]; a3 += hlo * __uint_as_float(u << 16); a3 += hhi * __uint_as_float(u & 0xffff0000u);
            }
        }
        ps[b_t][ct][0][kh] = a0; ps[b_t][ct][1][kh] = a1;
        ps[b_t][ct][2][kh] = a2; ps[b_t][ct][3][kh] = a3;
        __syncthreads();

        // ---- gate reduce + cell update (tid<128 owns (b, col)) ----
        if (tid < 128) {
            const int t_x = (dir == 0) ? s : (TT - 1 - s);
            const size_t m = (size_t)t_x * BB + bu;
            const int j = j0 + cu;
            const bf16* gr = gxd + m * G4 + j;
            const float g0 = ps[bu][cu][0][0] + ps[bu][cu][0][1] + bf2f(gr[0 * HH]);
            const float g1 = ps[bu][cu][1][0] + ps[bu][cu][1][1] + bf2f(gr[1 * HH]);
            const float g2 = ps[bu][cu][2][0] + ps[bu][cu][2][1] + bf2f(gr[2 * HH]);
            const float g3 = ps[bu][cu][3][0] + ps[bu][cu][3][1] + bf2f(gr[3 * HH]);
            const float ig = 1.f / (1.f + expf(-g0));
            const float fg = 1.f / (1.f + expf(-g1));
            const float gg = tanhf(g2);
            const float og = 1.f / (1.f + expf(-g3));
            c_state = fg * c_state + ig * gg;
            const float h = og * tanhf(c_state);

            dout[((size_t)bu * TT + t_x) * (2 * HH) + (size_t)dir * HH + j] = h;
            hslot[(size_t)((s + 1) & 1) * BH + (size_t)bu * HH + j] = f2bf(h);
            if (s == TT - 1) {
                const size_t hn_off = (size_t)BB * TT * 2 * HH;
                dout[hn_off + (size_t)dir * BH + (size_t)bu * HH + j] = h;
                dout[hn_off + 2 * (size_t)BH + (size_t)dir * BH + (size_t)bu * HH + j] = c_state;
            }
            __threadfence();   // make h_buf stores device-visible before arrival
        }
        __syncthreads();

        // ---- per-direction device barrier (monotonic counter) ----
        if (s < TT - 1) {
            if (tid == 0) {
                __hip_atomic_fetch_add(bar, 1u, __ATOMIC_RELEASE, __HIP_MEMORY_SCOPE_AGENT);
                const unsigned int target = (unsigned int)NWG_DIR * (unsigned int)(s + 1);
                while (__hip_atomic_load(bar, __ATOMIC_ACQUIRE, __HIP_MEMORY_SCOPE_AGENT) < target) {
                    __builtin_amdgcn_s_sleep(1);
                }
            }
            __syncthreads();
        }
    }
}

// ---------------------------------------------------------------------------
extern "C" void kernel_launch(void* const* d_in, const int* in_sizes, int n_in,
                              void* d_out, int out_size, void* d_ws, size_t ws_size,
                              hipStream_t stream)
{
    (void)in_sizes; (void)n_in; (void)out_size;
    const float* x     = (const float*)d_in[0];
    const float* h0    = (const float*)d_in[1];
    const float* c0    = (const float*)d_in[2];
    const float* wih_f = (const float*)d_in[3];
    const float* whh_f = (const float*)d_in[4];
    const float* bih_f = (const float*)d_in[5];
    const float* bhh_f = (const float*)d_in[6];
    const float* wih_r = (const float*)d_in[7];
    const float* whh_r = (const float*)d_in[8];
    const float* bih_r = (const float*)d_in[9];
    const float* bhh_r = (const float*)d_in[10];
    float* out = (float*)d_out;

    const size_t gx1 = (size_t)MM * G4 * sizeof(bf16);       // 64 MB per direction
    const size_t needA = 2 * gx1 + 4 * BH * sizeof(bf16) + 1024;
    char* ws = (char*)d_ws;

    if (ws_size >= needA) {
        // Plan A: both directions concurrently (256 WGs, 1/CU).
        bf16* gx = (bf16*)ws;
        bf16* h_buf = (bf16*)(ws + 2 * gx1);
        unsigned int* bars = (unsigned int*)(ws + 2 * gx1 + (size_t)4 * BH * sizeof(bf16));
        hipMemsetAsync(bars, 0, 512, stream);
        dim3 g1(MM / 64, G4 / 64, 2);
        proj_kernel<<<g1, 256, 0, stream>>>(x, wih_f, wih_r, bih_f, bhh_f, bih_r, bhh_r, gx, 0);
        lstm_rec_kernel<<<dim3(2 * NWG_DIR), dim3(256), 0, stream>>>(
            gx, h0, c0, whh_f, whh_r, out, h_buf, bars, 0);
    } else {
        // Plan B: sequential per-direction, single 64 MB gx buffer reused.
        bf16* gx = (bf16*)ws;
        bf16* h_buf = (bf16*)(ws + gx1);
        unsigned int* bars = (unsigned int*)(ws + gx1 + (size_t)2 * BH * sizeof(bf16));
        for (int d = 0; d < 2; ++d) {
            hipMemsetAsync(bars, 0, 512, stream);
            dim3 g1(MM / 64, G4 / 64, 1);
            proj_kernel<<<g1, 256, 0, stream>>>(x, wih_f, wih_r, bih_f, bhh_f, bih_r, bhh_r, gx, d);
            lstm_rec_kernel<<<dim3(NWG_DIR), dim3(256), 0, stream>>>(
                gx, h0, c0, whh_f, whh_r, out, h_buf, bars, d);
        }
    }
}

// Round 3
// 12759.259 us; speedup vs baseline: 1.3135x; 1.3135x over previous
//
#include <hip/hip_runtime.h>
#include <hip/hip_bf16.h>
#include <math.h>
#include <stdint.h>

#define BB 32
#define TT 512
#define II 512
#define HH 512
#define G4 (4 * HH)      // 2048
#define MM (TT * BB)     // 16384 rows of gx per direction
#define BH (BB * HH)     // 16384

typedef __hip_bfloat16 bf16;
typedef __attribute__((ext_vector_type(8))) short short8;   // 8 bf16 = 4 VGPRs
typedef __attribute__((ext_vector_type(4))) float f32x4;    // MFMA accumulator

__device__ __forceinline__ float bf2f(bf16 v) { return __bfloat162float(v); }
__device__ __forceinline__ bf16  f2bf(float v) { return __float2bfloat16(v); }
__device__ __forceinline__ short f2bs(float x) { bf16 v = f2bf(x); return *reinterpret_cast<short*>(&v); }
__device__ __forceinline__ float bs2f(short s) {
    unsigned u = ((unsigned)(unsigned short)s) << 16;
    return __uint_as_float(u);
}

// gx swizzled layout: [dl][t][wg 0..127][lane 0..63][e 0..7] bf16,
//   lane = b*2 + (jj>>1), e = (jj&1)*4 + gate   (b=batch, jj=j&3, j=h-col)
#define GX1 ((size_t)TT * 128 * 64 * 8)   // elements per direction (= MM*G4)

// ---------------------------------------------------------------------------
// Phase 1: input projection GEMM (fp32, 64x64 tile), epilogue writes gx in
// the phase-2 cell-update swizzle (bf16).
// ---------------------------------------------------------------------------
__global__ __launch_bounds__(256) void proj_kernel(
    const float* __restrict__ x,
    const float* __restrict__ w_f, const float* __restrict__ w_r,
    const float* __restrict__ bi_f, const float* __restrict__ bh_f,
    const float* __restrict__ bi_r, const float* __restrict__ bh_r,
    bf16* __restrict__ gx, int dir0)
{
    const int dl  = blockIdx.z;
    const int dir = dir0 + dl;
    const int m0 = blockIdx.x * 64;
    const int n0 = blockIdx.y * 64;
    const float* __restrict__ w  = dir ? w_r  : w_f;
    const float* __restrict__ bi = dir ? bi_r : bi_f;
    const float* __restrict__ bh = dir ? bh_r : bh_f;

    __shared__ __align__(16) float xs[16][68];
    __shared__ __align__(16) float ws[16][68];

    const int tid = threadIdx.x;
    const int tx = tid & 15, ty = tid >> 4;
    const int lm = tid >> 2, kq = tid & 3;

    const int ml = m0 + lm;
    const float* xrow = x + ((size_t)(ml & 31) * TT + (size_t)(ml >> 5)) * II;
    const float* wrow = w + (size_t)(n0 + lm) * II;

    float acc[4][4];
#pragma unroll
    for (int i = 0; i < 4; ++i)
#pragma unroll
        for (int j = 0; j < 4; ++j) acc[i][j] = 0.f;

    for (int k0 = 0; k0 < II; k0 += 16) {
        const float4 xv = *(const float4*)(xrow + k0 + kq * 4);
        const float4 wv = *(const float4*)(wrow + k0 + kq * 4);
        __syncthreads();
        xs[kq * 4 + 0][lm] = xv.x; xs[kq * 4 + 1][lm] = xv.y;
        xs[kq * 4 + 2][lm] = xv.z; xs[kq * 4 + 3][lm] = xv.w;
        ws[kq * 4 + 0][lm] = wv.x; ws[kq * 4 + 1][lm] = wv.y;
        ws[kq * 4 + 2][lm] = wv.z; ws[kq * 4 + 3][lm] = wv.w;
        __syncthreads();
#pragma unroll
        for (int kk = 0; kk < 16; ++kk) {
            const float4 a = *(const float4*)&xs[kk][ty * 4];
            const float4 b = *(const float4*)&ws[kk][tx * 4];
            acc[0][0] += a.x * b.x; acc[0][1] += a.x * b.y; acc[0][2] += a.x * b.z; acc[0][3] += a.x * b.w;
            acc[1][0] += a.y * b.x; acc[1][1] += a.y * b.y; acc[1][2] += a.y * b.z; acc[1][3] += a.y * b.w;
            acc[2][0] += a.z * b.x; acc[2][1] += a.z * b.y; acc[2][2] += a.z * b.z; acc[2][3] += a.z * b.w;
            acc[3][0] += a.w * b.x; acc[3][1] += a.w * b.y; acc[3][2] += a.w * b.z; acc[3][3] += a.w * b.w;
        }
    }

    float bias[4];
#pragma unroll
    for (int ni = 0; ni < 4; ++ni) {
        const int n = n0 + tx * 4 + ni;
        bias[ni] = bi[n] + bh[n];
    }
    bf16* gxd = gx + (size_t)dl * GX1;
#pragma unroll
    for (int mi = 0; mi < 4; ++mi) {
        const int m = m0 + ty * 4 + mi;
        const int t = m >> 5, b = m & 31;
#pragma unroll
        for (int ni = 0; ni < 4; ++ni) {
            const int n = n0 + tx * 4 + ni;
            const int g = n >> 9, jc = n & 511;
            const int wgp = jc >> 2, jp = jc & 3;
            const int lane = b * 2 + (jp >> 1);
            const int e = (jp & 1) * 4 + g;
            gxd[((((size_t)t * 128 + wgp) * 64 + lane) * 8 + e)] = f2bf(acc[mi][ni] + bias[ni]);
        }
    }
}

// ---------------------------------------------------------------------------
// Phase 2: MFMA recurrence. One wave (64 thr) per WG; WG (dl, wg) owns h-cols
// j0..j0+3 of its direction, computing all 4 gates as one packed N=16 MFMA
// tile (n = gate*4 + jj). Weights live in 64 VGPRs of B-fragments; A (=h)
// fragments load straight from global h_buf each step; gate exchange via a
// 2.3 KB LDS round-trip; per-direction 4-sub-counter device barrier.
// ---------------------------------------------------------------------------
__global__ __launch_bounds__(64, 1) void lstm_rec_kernel(
    const bf16* __restrict__ gx,
    const float* __restrict__ h0, const float* __restrict__ c0,
    const float* __restrict__ whh_f, const float* __restrict__ whh_r,
    float* __restrict__ dout,
    bf16* __restrict__ h_buf,          // [ndir][2 slots][BH]
    unsigned int* __restrict__ bars,   // [ndir][4 counters x 64 uints]
    int dir0)
{
    const int wgid = blockIdx.x;
    const int dl = wgid >> 7, wg = wgid & 127;
    const int dir = dir0 + dl;
    const int j0 = wg * 4;
    const int l = threadIdx.x;            // lane 0..63 (single wave)
    const float* __restrict__ whh = dir ? whh_r : whh_f;

    __shared__ __align__(16) float ex[16][36];   // [packed col][m row], pad->stride 36

    const int nl = l & 15;                // packed col index = gate*4 + jj
    const int g  = nl >> 2, jj = nl & 3;
    const int ko = (l >> 4) * 8;          // k-octet within a K=32 MFMA step

    // ---- B fragments (w_hh) resident in registers: 16 K-steps x 8 bf16 ----
    short8 bfrag[16];
    {
        const float* wr = whh + ((size_t)g * HH + (size_t)(j0 + jj)) * HH;
#pragma unroll
        for (int ks = 0; ks < 16; ++ks) {
            const float* p = wr + ks * 32 + ko;
            short8 t;
#pragma unroll
            for (int i = 0; i < 8; ++i) t[i] = f2bs(p[i]);
            bfrag[ks] = t;
        }
    }

    // cell-update role: lane handles cells (mC, jjA) and (mC, jjA+1)
    const int mC = l >> 1;
    const int jjA = (l & 1) * 2;

    float cs0, cs1;
    {
        const float* cp = c0 + (size_t)dir * BH + (size_t)mC * HH + j0 + jjA;
        cs0 = cp[0]; cs1 = cp[1];
    }

    bf16* hsl = h_buf + (size_t)dl * 2 * BH;
    const bf16* gxd = gx + (size_t)dl * GX1;
    unsigned int* barsd = bars + (size_t)dl * 256;

#pragma unroll 1
    for (int s = 0; s < TT; ++s) {
        const int t_x = dir ? (TT - 1 - s) : s;

        // gx prefetch: 8 bf16, coalesced dwordx4
        const short8 gxv = *(const short8*)(gxd + ((((size_t)t_x * 128 + wg) * 64 + l) * 8));

        // ---- MFMA: gates[32 x 16packed] = h[32 x 512] . W^T, K in 2 halves ----
        f32x4 acc0 = {0.f, 0.f, 0.f, 0.f};
        f32x4 acc1 = {0.f, 0.f, 0.f, 0.f};
#pragma unroll
        for (int half = 0; half < 2; ++half) {
            short8 a0[8], a1[8];
            if (s == 0) {
                const float* hb = h0 + (size_t)dir * BH;
#pragma unroll
                for (int k = 0; k < 8; ++k) {
                    const int ks = half * 8 + k;
                    const float* p0 = hb + (size_t)nl * HH + ks * 32 + ko;
                    const float* p1 = hb + (size_t)(nl + 16) * HH + ks * 32 + ko;
                    short8 t0, t1;
#pragma unroll
                    for (int i = 0; i < 8; ++i) { t0[i] = f2bs(p0[i]); t1[i] = f2bs(p1[i]); }
                    a0[k] = t0; a1[k] = t1;
                }
            } else {
                const bf16* hb = hsl + (size_t)(s & 1) * BH;
#pragma unroll
                for (int k = 0; k < 8; ++k) {
                    const int ks = half * 8 + k;
                    a0[k] = *(const short8*)(hb + (size_t)nl * HH + ks * 32 + ko);
                    a1[k] = *(const short8*)(hb + (size_t)(nl + 16) * HH + ks * 32 + ko);
                }
            }
#pragma unroll
            for (int k = 0; k < 8; ++k) {
                acc0 = __builtin_amdgcn_mfma_f32_16x16x32_bf16(a0[k], bfrag[half * 8 + k], acc0, 0, 0, 0);
                acc1 = __builtin_amdgcn_mfma_f32_16x16x32_bf16(a1[k], bfrag[half * 8 + k], acc1, 0, 0, 0);
            }
        }

        // ---- exchange C-layout -> cell layout through LDS ----
        {
            const int row0 = (l >> 4) * 4;            // C rows: (lane>>4)*4 + reg
            *(f32x4*)&ex[nl][row0]      = acc0;       // m-tile 0: rows 0..15
            *(f32x4*)&ex[nl][16 + row0] = acc1;       // m-tile 1: rows 16..31
        }
        // (compiler inserts lgkmcnt waits; single wave -> no barrier needed)

        float hv0, hv1;
#pragma unroll
        for (int c = 0; c < 2; ++c) {
            const int jc = jjA + c;
            float q0 = ex[0 * 4 + jc][mC] + bs2f(gxv[c * 4 + 0]);
            float q1 = ex[1 * 4 + jc][mC] + bs2f(gxv[c * 4 + 1]);
            float q2 = ex[2 * 4 + jc][mC] + bs2f(gxv[c * 4 + 2]);
            float q3 = ex[3 * 4 + jc][mC] + bs2f(gxv[c * 4 + 3]);
            q0 = fminf(fmaxf(q0, -30.f), 30.f);
            q1 = fminf(fmaxf(q1, -30.f), 30.f);
            q2 = fminf(fmaxf(q2, -30.f), 30.f);
            q3 = fminf(fmaxf(q3, -30.f), 30.f);
            const float ig = 1.f / (1.f + __expf(-q0));
            const float fg = 1.f / (1.f + __expf(-q1));
            const float te = __expf(2.f * q2);
            const float gg = (te - 1.f) / (te + 1.f);
            const float og = 1.f / (1.f + __expf(-q3));
            float cs = (c == 0) ? cs0 : cs1;
            cs = fg * cs + ig * gg;
            const float csc = fminf(fmaxf(cs, -15.f), 15.f);
            const float t2 = __expf(2.f * csc);
            const float th = (t2 - 1.f) / (t2 + 1.f);
            const float h = og * th;
            if (c == 0) { cs0 = cs; hv0 = h; } else { cs1 = cs; hv1 = h; }
        }

        // ---- writes: dout (fp32), next-step h_buf (bf16) ----
        {
            float2 ho; ho.x = hv0; ho.y = hv1;
            *(float2*)(dout + ((size_t)mC * TT + t_x) * (2 * HH) + (size_t)dir * HH + j0 + jjA) = ho;

            bf16 hb0 = f2bf(hv0), hb1 = f2bf(hv1);
            unsigned pk = (unsigned)*(unsigned short*)&hb0 |
                          ((unsigned)*(unsigned short*)&hb1 << 16);
            *(unsigned*)(hsl + (size_t)((s + 1) & 1) * BH + (size_t)mC * HH + j0 + jjA) = pk;

            if (s == TT - 1) {
                const size_t hn_off = (size_t)BB * TT * 2 * HH;
                float2 co; co.x = cs0; co.y = cs1;
                *(float2*)(dout + hn_off + (size_t)dir * BH + (size_t)mC * HH + j0 + jjA) = ho;
                *(float2*)(dout + hn_off + 2 * (size_t)BH + (size_t)dir * BH + (size_t)mC * HH + j0 + jjA) = co;
            }
        }

        // ---- per-direction device barrier: 4 sub-counters, 32 arrivals each ----
        if (s < TT - 1) {
            __threadfence();
            if (l == 0) {
                __hip_atomic_fetch_add(barsd + (wg & 3) * 64, 1u,
                                       __ATOMIC_RELEASE, __HIP_MEMORY_SCOPE_AGENT);
            }
            const unsigned tgt = 32u * (unsigned)(s + 1);
            if (l < 4) {
                while (__hip_atomic_load(barsd + l * 64,
                                         __ATOMIC_ACQUIRE, __HIP_MEMORY_SCOPE_AGENT) < tgt) {
                    __builtin_amdgcn_s_sleep(1);
                }
            }
            __threadfence();   // wave-wide acquire before next step's h_buf reads
        }
    }
}

// ---------------------------------------------------------------------------
extern "C" void kernel_launch(void* const* d_in, const int* in_sizes, int n_in,
                              void* d_out, int out_size, void* d_ws, size_t ws_size,
                              hipStream_t stream)
{
    (void)in_sizes; (void)n_in; (void)out_size;
    const float* x     = (const float*)d_in[0];
    const float* h0    = (const float*)d_in[1];
    const float* c0    = (const float*)d_in[2];
    const float* wih_f = (const float*)d_in[3];
    const float* whh_f = (const float*)d_in[4];
    const float* bih_f = (const float*)d_in[5];
    const float* bhh_f = (const float*)d_in[6];
    const float* wih_r = (const float*)d_in[7];
    const float* whh_r = (const float*)d_in[8];
    const float* bih_r = (const float*)d_in[9];
    const float* bhh_r = (const float*)d_in[10];
    float* out = (float*)d_out;

    const size_t gx1 = GX1 * sizeof(bf16);                   // 64 MB per direction
    const size_t needA = 2 * gx1 + (size_t)4 * BH * sizeof(bf16) + 4096;
    char* ws = (char*)d_ws;

    if (ws_size >= needA) {
        // Plan A: both directions concurrently (256 single-wave WGs).
        bf16* gx = (bf16*)ws;
        bf16* h_buf = (bf16*)(ws + 2 * gx1);
        unsigned int* bars = (unsigned int*)(ws + 2 * gx1 + (size_t)4 * BH * sizeof(bf16));
        hipMemsetAsync(bars, 0, 2048, stream);
        dim3 g1(MM / 64, G4 / 64, 2);
        proj_kernel<<<g1, 256, 0, stream>>>(x, wih_f, wih_r, bih_f, bhh_f, bih_r, bhh_r, gx, 0);
        lstm_rec_kernel<<<dim3(256), dim3(64), 0, stream>>>(
            gx, h0, c0, whh_f, whh_r, out, h_buf, bars, 0);
    } else {
        // Plan B: sequential per-direction, single 64 MB gx buffer reused.
        bf16* gx = (bf16*)ws;
        bf16* h_buf = (bf16*)(ws + gx1);
        unsigned int* bars = (unsigned int*)(ws + gx1 + (size_t)2 * BH * sizeof(bf16));
        for (int d = 0; d < 2; ++d) {
            hipMemsetAsync(bars, 0, 2048, stream);
            dim3 g1(MM / 64, G4 / 64, 1);
            proj_kernel<<<g1, 256, 0, stream>>>(x, wih_f, wih_r, bih_f, bhh_f, bih_r, bhh_r, gx, d);
            lstm_rec_kernel<<<dim3(128), dim3(64), 0, stream>>>(
                gx, h0, c0, whh_f, whh_r, out, h_buf, bars, d);
        }
    }
}

// Round 4
// 3134.799 us; speedup vs baseline: 5.3461x; 4.0702x over previous
//
#include <hip/hip_runtime.h>
#include <hip/hip_bf16.h>
#include <math.h>
#include <stdint.h>

#define BB 32
#define TT 512
#define II 512
#define HH 512
#define G4 (4 * HH)      // 2048
#define MM (TT * BB)     // 16384 rows of gx per direction
#define BH (BB * HH)     // 16384
#define WGD 32           // workgroups per direction in rec kernel (4 waves each)

typedef __hip_bfloat16 bf16;
typedef __attribute__((ext_vector_type(8))) short short8;   // 8 bf16 = 4 VGPRs
typedef __attribute__((ext_vector_type(4))) float f32x4;    // MFMA accumulator

__device__ __forceinline__ float bf2f(bf16 v) { return __bfloat162float(v); }
__device__ __forceinline__ bf16  f2bf(float v) { return __float2bfloat16(v); }
__device__ __forceinline__ short f2bs(float x) { bf16 v = f2bf(x); return *reinterpret_cast<short*>(&v); }
__device__ __forceinline__ float bs2f(short s) {
    unsigned u = ((unsigned)(unsigned short)s) << 16;
    return __uint_as_float(u);
}

// gx swizzled layout: [dl][t][cg 0..127][lane 0..63][e 0..7] bf16,
//   lane = b*2 + (jj>>1), e = (jj&1)*4 + gate   (b=batch, jj=j&3, cg=j>>2)
#define GX1 ((size_t)TT * 128 * 64 * 8)   // elements per direction (= MM*G4)

// ---------------------------------------------------------------------------
// Phase 1: input projection GEMM (fp32, 64x64 tile), epilogue writes gx in
// the phase-2 cell-update swizzle (bf16).
// ---------------------------------------------------------------------------
__global__ __launch_bounds__(256) void proj_kernel(
    const float* __restrict__ x,
    const float* __restrict__ w_f, const float* __restrict__ w_r,
    const float* __restrict__ bi_f, const float* __restrict__ bh_f,
    const float* __restrict__ bi_r, const float* __restrict__ bh_r,
    bf16* __restrict__ gx, int dir0)
{
    const int dl  = blockIdx.z;
    const int dir = dir0 + dl;
    const int m0 = blockIdx.x * 64;
    const int n0 = blockIdx.y * 64;
    const float* __restrict__ w  = dir ? w_r  : w_f;
    const float* __restrict__ bi = dir ? bi_r : bi_f;
    const float* __restrict__ bh = dir ? bh_r : bh_f;

    __shared__ __align__(16) float xs[16][68];
    __shared__ __align__(16) float ws[16][68];

    const int tid = threadIdx.x;
    const int tx = tid & 15, ty = tid >> 4;
    const int lm = tid >> 2, kq = tid & 3;

    const int ml = m0 + lm;
    const float* xrow = x + ((size_t)(ml & 31) * TT + (size_t)(ml >> 5)) * II;
    const float* wrow = w + (size_t)(n0 + lm) * II;

    float acc[4][4];
#pragma unroll
    for (int i = 0; i < 4; ++i)
#pragma unroll
        for (int j = 0; j < 4; ++j) acc[i][j] = 0.f;

    for (int k0 = 0; k0 < II; k0 += 16) {
        const float4 xv = *(const float4*)(xrow + k0 + kq * 4);
        const float4 wv = *(const float4*)(wrow + k0 + kq * 4);
        __syncthreads();
        xs[kq * 4 + 0][lm] = xv.x; xs[kq * 4 + 1][lm] = xv.y;
        xs[kq * 4 + 2][lm] = xv.z; xs[kq * 4 + 3][lm] = xv.w;
        ws[kq * 4 + 0][lm] = wv.x; ws[kq * 4 + 1][lm] = wv.y;
        ws[kq * 4 + 2][lm] = wv.z; ws[kq * 4 + 3][lm] = wv.w;
        __syncthreads();
#pragma unroll
        for (int kk = 0; kk < 16; ++kk) {
            const float4 a = *(const float4*)&xs[kk][ty * 4];
            const float4 b = *(const float4*)&ws[kk][tx * 4];
            acc[0][0] += a.x * b.x; acc[0][1] += a.x * b.y; acc[0][2] += a.x * b.z; acc[0][3] += a.x * b.w;
            acc[1][0] += a.y * b.x; acc[1][1] += a.y * b.y; acc[1][2] += a.y * b.z; acc[1][3] += a.y * b.w;
            acc[2][0] += a.z * b.x; acc[2][1] += a.z * b.y; acc[2][2] += a.z * b.z; acc[2][3] += a.z * b.w;
            acc[3][0] += a.w * b.x; acc[3][1] += a.w * b.y; acc[3][2] += a.w * b.z; acc[3][3] += a.w * b.w;
        }
    }

    float bias[4];
#pragma unroll
    for (int ni = 0; ni < 4; ++ni) {
        const int n = n0 + tx * 4 + ni;
        bias[ni] = bi[n] + bh[n];
    }
    bf16* gxd = gx + (size_t)dl * GX1;
#pragma unroll
    for (int mi = 0; mi < 4; ++mi) {
        const int m = m0 + ty * 4 + mi;
        const int t = m >> 5, b = m & 31;
#pragma unroll
        for (int ni = 0; ni < 4; ++ni) {
            const int n = n0 + tx * 4 + ni;
            const int g = n >> 9, jc = n & 511;
            const int cg = jc >> 2, jp = jc & 3;
            const int lane = b * 2 + (jp >> 1);
            const int e = (jp & 1) * 4 + g;
            gxd[((((size_t)t * 128 + cg) * 64 + lane) * 8 + e)] = f2bf(acc[mi][ni] + bias[ni]);
        }
    }
}

// ---------------------------------------------------------------------------
// Phase 2: MFMA recurrence, 4-wave WGs, no release/acquire fences.
// WG (dl, wgl) = 4 waves; wave wv owns col-group cg = wgl*4+wv (4 h-cols),
// computing all 4 gates as one packed N=16 MFMA tile. Weights in VGPRs;
// h staged cooperatively into LDS once per step (plain loads after one
// buffer_inv sc1); h published via relaxed agent stores (write-through,
// no dirty L2); barrier = waitcnt + relaxed atomic add + relaxed polls.
// ---------------------------------------------------------------------------
__global__ __launch_bounds__(256, 1) void lstm_rec_kernel(
    const bf16* __restrict__ gx,
    const float* __restrict__ h0, const float* __restrict__ c0,
    const float* __restrict__ whh_f, const float* __restrict__ whh_r,
    float* __restrict__ dout,
    bf16* __restrict__ h_buf,          // [ndir][2 slots][BH]
    unsigned int* __restrict__ bars,   // [ndir][4 counters x 64 uints]
    int dir0)
{
    const int dl  = blockIdx.x >> 5;
    const int wgl = blockIdx.x & 31;
    const int dir = dir0 + dl;
    const int tid = threadIdx.x;
    const int wv  = tid >> 6;            // wave 0..3
    const int l   = tid & 63;            // lane
    const int cg  = wgl * 4 + wv;        // col-group 0..127
    const int j0  = cg * 4;
    const float* __restrict__ whh = dir ? whh_r : whh_f;
    unsigned int* barsd = bars + (size_t)dl * 256;

    __shared__ __align__(16) bf16 h_s[32][520];   // staged h, +8 pad
    __shared__ __align__(16) float ex[4][16][36]; // per-wave gate exchange

    const int nl = l & 15;                // packed col index = gate*4 + jj
    const int g  = nl >> 2, jj = nl & 3;
    const int ko = (l >> 4) * 8;          // k-octet within a K=32 MFMA step

    // ---- B fragments (w_hh) resident in registers: 16 K-steps x 8 bf16 ----
    short8 bfrag[16];
    {
        const float* wr = whh + ((size_t)g * HH + (size_t)(j0 + jj)) * HH;
#pragma unroll
        for (int ks = 0; ks < 16; ++ks) {
            const float* p = wr + ks * 32 + ko;
            short8 t;
#pragma unroll
            for (int i = 0; i < 8; ++i) t[i] = f2bs(p[i]);
            bfrag[ks] = t;
        }
    }

    // cell-update role: lane handles cells (mC, jjA) and (mC, jjA+1)
    const int mC = l >> 1;
    const int jjA = (l & 1) * 2;

    float cs0, cs1;
    {
        const float* cp = c0 + (size_t)dir * BH + (size_t)mC * HH + j0 + jjA;
        cs0 = cp[0]; cs1 = cp[1];
    }

    bf16* hsl = h_buf + (size_t)dl * 2 * BH;
    const bf16* gxd = gx + (size_t)dl * GX1;

    // ---- stage initial h (fp32 h0 -> bf16 LDS) ----
    for (int q = 0; q < 64; ++q) {
        const int f = q * 256 + tid;      // 0..16383 = b*512+k
        h_s[f >> 9][f & 511] = f2bf(h0[(size_t)dir * BH + f]);
    }
    __syncthreads();

    // first gx fetch
    short8 gxv = *(const short8*)(gxd + ((((size_t)(dir ? TT - 1 : 0) * 128 + cg) * 64 + l) * 8));

#pragma unroll 1
    for (int s = 0; s < TT; ++s) {
        const int t_x = dir ? (TT - 1 - s) : s;

        // ---- MFMA: gates[32 x 16packed] = h . W^T, A from LDS ----
        f32x4 acc0 = {0.f, 0.f, 0.f, 0.f};
        f32x4 acc1 = {0.f, 0.f, 0.f, 0.f};
#pragma unroll
        for (int half = 0; half < 2; ++half) {
            short8 a0[8], a1[8];
#pragma unroll
            for (int k = 0; k < 8; ++k) {
                const int ks = half * 8 + k;
                a0[k] = *(const short8*)&h_s[nl][ks * 32 + ko];
                a1[k] = *(const short8*)&h_s[nl + 16][ks * 32 + ko];
            }
#pragma unroll
            for (int k = 0; k < 8; ++k) {
                acc0 = __builtin_amdgcn_mfma_f32_16x16x32_bf16(a0[k], bfrag[half * 8 + k], acc0, 0, 0, 0);
                acc1 = __builtin_amdgcn_mfma_f32_16x16x32_bf16(a1[k], bfrag[half * 8 + k], acc1, 0, 0, 0);
            }
        }

        // ---- exchange C-layout -> cell layout through per-wave LDS slice ----
        {
            const int row0 = (l >> 4) * 4;            // C rows: (lane>>4)*4 + reg
            *(f32x4*)&ex[wv][nl][row0]      = acc0;   // m-tile 0: rows 0..15
            *(f32x4*)&ex[wv][nl][16 + row0] = acc1;   // m-tile 1: rows 16..31
        }
        // single-wave producer/consumer: compiler inserts lgkmcnt waits

        float hv0, hv1;
#pragma unroll
        for (int c = 0; c < 2; ++c) {
            const int jc = jjA + c;
            float q0 = ex[wv][0 * 4 + jc][mC] + bs2f(gxv[c * 4 + 0]);
            float q1 = ex[wv][1 * 4 + jc][mC] + bs2f(gxv[c * 4 + 1]);
            float q2 = ex[wv][2 * 4 + jc][mC] + bs2f(gxv[c * 4 + 2]);
            float q3 = ex[wv][3 * 4 + jc][mC] + bs2f(gxv[c * 4 + 3]);
            q0 = fminf(fmaxf(q0, -30.f), 30.f);
            q1 = fminf(fmaxf(q1, -30.f), 30.f);
            q2 = fminf(fmaxf(q2, -30.f), 30.f);
            q3 = fminf(fmaxf(q3, -30.f), 30.f);
            const float ig = 1.f / (1.f + __expf(-q0));
            const float fg = 1.f / (1.f + __expf(-q1));
            const float te = __expf(2.f * q2);
            const float gg = (te - 1.f) / (te + 1.f);
            const float og = 1.f / (1.f + __expf(-q3));
            float cs = (c == 0) ? cs0 : cs1;
            cs = fg * cs + ig * gg;
            const float csc = fminf(fmaxf(cs, -15.f), 15.f);
            const float t2 = __expf(2.f * csc);
            const float th = (t2 - 1.f) / (t2 + 1.f);
            const float h = og * th;
            if (c == 0) { cs0 = cs; hv0 = h; } else { cs1 = cs; hv1 = h; }
        }

        // ---- writes: dout (fp32, plain) + h publish (relaxed agent store) ----
        {
            float2 ho; ho.x = hv0; ho.y = hv1;
            *(float2*)(dout + ((size_t)mC * TT + t_x) * (2 * HH) + (size_t)dir * HH + j0 + jjA) = ho;

            bf16 hb0 = f2bf(hv0), hb1 = f2bf(hv1);
            unsigned pk = (unsigned)*(unsigned short*)&hb0 |
                          ((unsigned)*(unsigned short*)&hb1 << 16);
            unsigned* hp = (unsigned*)(hsl + (size_t)((s + 1) & 1) * BH + (size_t)mC * HH + j0 + jjA);
            __hip_atomic_store(hp, pk, __ATOMIC_RELAXED, __HIP_MEMORY_SCOPE_AGENT);

            if (s == TT - 1) {
                const size_t hn_off = (size_t)BB * TT * 2 * HH;
                float2 co; co.x = cs0; co.y = cs1;
                *(float2*)(dout + hn_off + (size_t)dir * BH + (size_t)mC * HH + j0 + jjA) = ho;
                *(float2*)(dout + hn_off + 2 * (size_t)BH + (size_t)dir * BH + (size_t)mC * HH + j0 + jjA) = co;
            }
        }

        // ---- barrier + restage (skip after last step) ----
        if (s < TT - 1) {
            asm volatile("s_waitcnt vmcnt(0)" ::: "memory");  // h publish complete
            __syncthreads();                                   // whole WG done
            if (tid == 0)
                __hip_atomic_fetch_add(barsd + (wgl & 3) * 64, 1u,
                                       __ATOMIC_RELAXED, __HIP_MEMORY_SCOPE_AGENT);
            // prefetch next gx while spinning
            const int t_n = dir ? (TT - 2 - s) : (s + 1);
            const short8 gx_next = *(const short8*)(gxd + ((((size_t)t_n * 128 + cg) * 64 + l) * 8));

            if (wv == 0 && l < 4) {
                const unsigned tgt = (unsigned)(WGD / 4) * (unsigned)(s + 1);
                while (__hip_atomic_load(barsd + l * 64,
                                         __ATOMIC_RELAXED, __HIP_MEMORY_SCOPE_AGENT) < tgt) {
                    __builtin_amdgcn_s_sleep(1);
                }
            }
            if (wv == 0)
                asm volatile("buffer_inv sc1" ::: "memory");   // drop stale L1/L2 h lines
            __syncthreads();

            // cooperative stage of h slot (s+1)&1 : 32 KB, plain dwordx4 loads
            const uint4* src = (const uint4*)(hsl + (size_t)((s + 1) & 1) * BH);
#pragma unroll
            for (int q = 0; q < 8; ++q) {
                const int f16 = q * 256 + tid;       // 16B-chunk index, 2048 total
                const uint4 v = src[f16];
                const int e = f16 * 8;               // element index
                *(uint4*)&h_s[e >> 9][e & 511] = v;
            }
            __syncthreads();
            gxv = gx_next;
        }
    }
}

// ---------------------------------------------------------------------------
extern "C" void kernel_launch(void* const* d_in, const int* in_sizes, int n_in,
                              void* d_out, int out_size, void* d_ws, size_t ws_size,
                              hipStream_t stream)
{
    (void)in_sizes; (void)n_in; (void)out_size;
    const float* x     = (const float*)d_in[0];
    const float* h0    = (const float*)d_in[1];
    const float* c0    = (const float*)d_in[2];
    const float* wih_f = (const float*)d_in[3];
    const float* whh_f = (const float*)d_in[4];
    const float* bih_f = (const float*)d_in[5];
    const float* bhh_f = (const float*)d_in[6];
    const float* wih_r = (const float*)d_in[7];
    const float* whh_r = (const float*)d_in[8];
    const float* bih_r = (const float*)d_in[9];
    const float* bhh_r = (const float*)d_in[10];
    float* out = (float*)d_out;

    const size_t gx1 = GX1 * sizeof(bf16);                   // 64 MB per direction
    const size_t needA = 2 * gx1 + (size_t)4 * BH * sizeof(bf16) + 4096;
    char* ws = (char*)d_ws;

    if (ws_size >= needA) {
        // Plan A: both directions concurrently (64 4-wave WGs).
        bf16* gx = (bf16*)ws;
        bf16* h_buf = (bf16*)(ws + 2 * gx1);
        unsigned int* bars = (unsigned int*)(ws + 2 * gx1 + (size_t)4 * BH * sizeof(bf16));
        hipMemsetAsync(bars, 0, 2048, stream);
        dim3 g1(MM / 64, G4 / 64, 2);
        proj_kernel<<<g1, 256, 0, stream>>>(x, wih_f, wih_r, bih_f, bhh_f, bih_r, bhh_r, gx, 0);
        lstm_rec_kernel<<<dim3(2 * WGD), dim3(256), 0, stream>>>(
            gx, h0, c0, whh_f, whh_r, out, h_buf, bars, 0);
    } else {
        // Plan B: sequential per-direction, single 64 MB gx buffer reused.
        bf16* gx = (bf16*)ws;
        bf16* h_buf = (bf16*)(ws + gx1);
        unsigned int* bars = (unsigned int*)(ws + gx1 + (size_t)2 * BH * sizeof(bf16));
        for (int d = 0; d < 2; ++d) {
            hipMemsetAsync(bars, 0, 2048, stream);
            dim3 g1(MM / 64, G4 / 64, 1);
            proj_kernel<<<g1, 256, 0, stream>>>(x, wih_f, wih_r, bih_f, bhh_f, bih_r, bhh_r, gx, d);
            lstm_rec_kernel<<<dim3(WGD), dim3(256), 0, stream>>>(
                gx, h0, c0, whh_f, whh_r, out, h_buf, bars, d);
        }
    }
}

// Round 5
// 2292.228 us; speedup vs baseline: 7.3113x; 1.3676x over previous
//
#include <hip/hip_runtime.h>
#include <hip/hip_bf16.h>
#include <math.h>
#include <stdint.h>

#define BB 32
#define TT 512
#define II 512
#define HH 512
#define G4 (4 * HH)      // 2048
#define MM (TT * BB)     // 16384 rows of gx per direction
#define BH (BB * HH)     // 16384
#define WGD 32           // workgroups per direction in rec kernel (4 waves each)

typedef __hip_bfloat16 bf16;
typedef __attribute__((ext_vector_type(8))) short short8;   // 8 bf16 = 4 VGPRs
typedef __attribute__((ext_vector_type(4))) float f32x4;    // MFMA accumulator

__device__ __forceinline__ float bf2f(bf16 v) { return __bfloat162float(v); }
__device__ __forceinline__ bf16  f2bf(float v) { return __float2bfloat16(v); }
__device__ __forceinline__ short f2bs(float x) { bf16 v = f2bf(x); return *reinterpret_cast<short*>(&v); }
__device__ __forceinline__ float bs2f(short s) {
    unsigned u = ((unsigned)(unsigned short)s) << 16;
    return __uint_as_float(u);
}
__device__ __forceinline__ short8 pk8(float4 u, float4 v) {
    short8 t;
    t[0] = f2bs(u.x); t[1] = f2bs(u.y); t[2] = f2bs(u.z); t[3] = f2bs(u.w);
    t[4] = f2bs(v.x); t[5] = f2bs(v.y); t[6] = f2bs(v.z); t[7] = f2bs(v.w);
    return t;
}

// gx gate-planar swizzle: [dl][t][g][cg 0..127][b*4 + jj] bf16
//   (b=batch 0..31, jj=j&3, cg=j>>2). Per (t,g,cg): 128 contiguous bf16.
//   rec lane l of col-group cg reads dword (2 cells) at elem offset l*2.
#define GX1 ((size_t)TT * 4 * 128 * 128)   // elements per direction (= MM*G4)

// ---------------------------------------------------------------------------
// Phase 1: input projection GEMM via MFMA (bf16 in / fp32 acc).
// Block 256 thr = 4 waves, tile M=64 x N=128, K-tile 32, 16 K-iters.
// Wave wv owns m-rows [wv*16, wv*16+16), 8 n-tiles of 16.
// Staging converts fp32 x / w_ih to bf16 in-register (no extra workspace).
// Epilogue: C -> LDS transpose -> fully coalesced 16B gx stores.
// ---------------------------------------------------------------------------
__global__ __launch_bounds__(256) void proj_mfma_kernel(
    const float* __restrict__ x,
    const float* __restrict__ w_f, const float* __restrict__ w_r,
    const float* __restrict__ bi_f, const float* __restrict__ bh_f,
    const float* __restrict__ bi_r, const float* __restrict__ bh_r,
    bf16* __restrict__ gx, int dir0)
{
    const int dl = blockIdx.z, dir = dir0 + dl;
    const int m0 = blockIdx.x * 64;
    const int n0 = blockIdx.y * 128;
    const float* __restrict__ w  = dir ? w_r  : w_f;
    const float* __restrict__ bi = dir ? bi_r : bi_f;
    const float* __restrict__ bh = dir ? bh_r : bh_f;

    __shared__ __align__(16) char smem[17408];
    bf16 (*As)[40]  = (bf16(*)[40])smem;            // 64 x (32+8 pad)
    bf16 (*Bs)[40]  = (bf16(*)[40])(smem + 5120);   // 128 x (32+8 pad)
    bf16 (*Cs)[136] = (bf16(*)[136])smem;           // 64 x 136 (reuses smem)

    const int tid = threadIdx.x;
    const int wv = tid >> 6, l = tid & 63;
    const int nl = l & 15, ko = (l >> 4) * 8;

    // A staging: row a_r = tid>>2 (0..63), seg a_s = tid&3 (8 elems of 32)
    const int a_r = tid >> 2, a_s = tid & 3;
    const float* a_src = x + ((size_t)((m0 + a_r) & 31) * TT + (size_t)((m0 + a_r) >> 5)) * II + a_s * 8;
    // B staging: row b_r = tid>>1 (0..127), half b_h = tid&1 (16 elems)
    const int b_r = tid >> 1, b_h = tid & 1;
    const float* b_src = w + (size_t)(n0 + b_r) * II + b_h * 16;

    f32x4 acc[8];
#pragma unroll
    for (int j = 0; j < 8; ++j) acc[j] = (f32x4){0.f, 0.f, 0.f, 0.f};

    float bias[8];
#pragma unroll
    for (int j = 0; j < 8; ++j) {
        const int n = n0 + j * 16 + nl;
        bias[j] = bi[n] + bh[n];
    }

    for (int k0 = 0; k0 < II; k0 += 32) {
        const float4 av0 = *(const float4*)(a_src + k0);
        const float4 av1 = *(const float4*)(a_src + k0 + 4);
        const float4 bv0 = *(const float4*)(b_src + k0);
        const float4 bv1 = *(const float4*)(b_src + k0 + 4);
        const float4 bv2 = *(const float4*)(b_src + k0 + 8);
        const float4 bv3 = *(const float4*)(b_src + k0 + 12);
        __syncthreads();   // previous tile fully consumed
        *(short8*)&As[a_r][a_s * 8] = pk8(av0, av1);
        *(short8*)&Bs[b_r][b_h * 16]     = pk8(bv0, bv1);
        *(short8*)&Bs[b_r][b_h * 16 + 8] = pk8(bv2, bv3);
        __syncthreads();
        const short8 a = *(const short8*)&As[wv * 16 + nl][ko];
#pragma unroll
        for (int j = 0; j < 8; ++j) {
            const short8 b = *(const short8*)&Bs[j * 16 + nl][ko];
            acc[j] = __builtin_amdgcn_mfma_f32_16x16x32_bf16(a, b, acc[j], 0, 0, 0);
        }
    }

    // ---- epilogue: C tiles -> Cs (LDS) -> coalesced gx3 stores ----
    __syncthreads();                       // all ds_reads done before Cs overwrite
    const int row0 = (l >> 4) * 4;
#pragma unroll
    for (int j = 0; j < 8; ++j)
#pragma unroll
        for (int r = 0; r < 4; ++r)
            Cs[wv * 16 + row0 + r][j * 16 + nl] = f2bf(acc[j][r] + bias[j]);
    __syncthreads();

    bf16* gxd = gx + (size_t)dl * GX1;
    const int g   = n0 >> 9;               // gate (N-tile lies inside one gate)
    const int cgb = (n0 & 511) >> 2;       // col-group base
    const int t_base = blockIdx.x * 2;
#pragma unroll
    for (int i = 0; i < 4; ++i) {
        const int c = i * 256 + tid;       // 0..1023 16B-chunks
        const int tl = c >> 9, cgl = (c >> 4) & 31, u = c & 15;
        const int r0 = tl * 32 + 2 * u;
        const uint2 lo = *(const uint2*)&Cs[r0][cgl * 4];
        const uint2 hi = *(const uint2*)&Cs[r0 + 1][cgl * 4];
        uint4 ov; ov.x = lo.x; ov.y = lo.y; ov.z = hi.x; ov.w = hi.y;
        *(uint4*)(gxd + ((((size_t)(t_base + tl) * 4 + g) * 128 + cgb + cgl) * 128 + u * 8)) = ov;
    }
}

// ---------------------------------------------------------------------------
// Phase 2: MFMA recurrence, 4-wave WGs, no release/acquire fences.
// (unchanged from Round 4 except gate-planar gx reads: 4 coalesced dwords.)
// ---------------------------------------------------------------------------
__global__ __launch_bounds__(256, 1) void lstm_rec_kernel(
    const bf16* __restrict__ gx,
    const float* __restrict__ h0, const float* __restrict__ c0,
    const float* __restrict__ whh_f, const float* __restrict__ whh_r,
    float* __restrict__ dout,
    bf16* __restrict__ h_buf,          // [ndir][2 slots][BH]
    unsigned int* __restrict__ bars,   // [ndir][4 counters x 64 uints]
    int dir0)
{
    const int dl  = blockIdx.x >> 5;
    const int wgl = blockIdx.x & 31;
    const int dir = dir0 + dl;
    const int tid = threadIdx.x;
    const int wv  = tid >> 6;            // wave 0..3
    const int l   = tid & 63;            // lane
    const int cg  = wgl * 4 + wv;        // col-group 0..127
    const int j0  = cg * 4;
    const float* __restrict__ whh = dir ? whh_r : whh_f;
    unsigned int* barsd = bars + (size_t)dl * 256;

    __shared__ __align__(16) bf16 h_s[32][520];   // staged h, +8 pad
    __shared__ __align__(16) float ex[4][16][36]; // per-wave gate exchange

    const int nl = l & 15;                // packed col index = gate*4 + jj
    const int g  = nl >> 2, jj = nl & 3;
    const int ko = (l >> 4) * 8;          // k-octet within a K=32 MFMA step

    // ---- B fragments (w_hh) resident in registers: 16 K-steps x 8 bf16 ----
    short8 bfrag[16];
    {
        const float* wr = whh + ((size_t)g * HH + (size_t)(j0 + jj)) * HH;
#pragma unroll
        for (int ks = 0; ks < 16; ++ks) {
            const float* p = wr + ks * 32 + ko;
            short8 t;
#pragma unroll
            for (int i = 0; i < 8; ++i) t[i] = f2bs(p[i]);
            bfrag[ks] = t;
        }
    }

    // cell-update role: lane handles cells (mC, jjA) and (mC, jjA+1)
    const int mC = l >> 1;
    const int jjA = (l & 1) * 2;

    float cs0, cs1;
    {
        const float* cp = c0 + (size_t)dir * BH + (size_t)mC * HH + j0 + jjA;
        cs0 = cp[0]; cs1 = cp[1];
    }

    bf16* hsl = h_buf + (size_t)dl * 2 * BH;
    const unsigned* gxw = (const unsigned*)(gx + (size_t)dl * GX1);

    // ---- stage initial h (fp32 h0 -> bf16 LDS) ----
    for (int q = 0; q < 64; ++q) {
        const int f = q * 256 + tid;      // 0..16383 = b*512+k
        h_s[f >> 9][f & 511] = f2bf(h0[(size_t)dir * BH + f]);
    }
    __syncthreads();

    // first gx fetch: 4 gate-planar dwords (2 cells each)
    unsigned gw[4];
    {
        const int t0 = dir ? (TT - 1) : 0;
#pragma unroll
        for (int gg = 0; gg < 4; ++gg)
            gw[gg] = gxw[((size_t)(t0 * 4 + gg) * 128 + cg) * 64 + l];
    }

#pragma unroll 1
    for (int s = 0; s < TT; ++s) {
        const int t_x = dir ? (TT - 1 - s) : s;

        // ---- MFMA: gates[32 x 16packed] = h . W^T, A from LDS ----
        f32x4 acc0 = {0.f, 0.f, 0.f, 0.f};
        f32x4 acc1 = {0.f, 0.f, 0.f, 0.f};
#pragma unroll
        for (int half = 0; half < 2; ++half) {
            short8 a0[8], a1[8];
#pragma unroll
            for (int k = 0; k < 8; ++k) {
                const int ks = half * 8 + k;
                a0[k] = *(const short8*)&h_s[nl][ks * 32 + ko];
                a1[k] = *(const short8*)&h_s[nl + 16][ks * 32 + ko];
            }
#pragma unroll
            for (int k = 0; k < 8; ++k) {
                acc0 = __builtin_amdgcn_mfma_f32_16x16x32_bf16(a0[k], bfrag[half * 8 + k], acc0, 0, 0, 0);
                acc1 = __builtin_amdgcn_mfma_f32_16x16x32_bf16(a1[k], bfrag[half * 8 + k], acc1, 0, 0, 0);
            }
        }

        // ---- exchange C-layout -> cell layout through per-wave LDS slice ----
        {
            const int row0 = (l >> 4) * 4;            // C rows: (lane>>4)*4 + reg
            *(f32x4*)&ex[wv][nl][row0]      = acc0;   // m-tile 0: rows 0..15
            *(f32x4*)&ex[wv][nl][16 + row0] = acc1;   // m-tile 1: rows 16..31
        }
        // single-wave producer/consumer: compiler inserts lgkmcnt waits

        float hv0, hv1;
#pragma unroll
        for (int c = 0; c < 2; ++c) {
            const int jc = jjA + c;
            const int sh = 16 * c;
            float q0 = ex[wv][0 * 4 + jc][mC] + bs2f((short)(gw[0] >> sh));
            float q1 = ex[wv][1 * 4 + jc][mC] + bs2f((short)(gw[1] >> sh));
            float q2 = ex[wv][2 * 4 + jc][mC] + bs2f((short)(gw[2] >> sh));
            float q3 = ex[wv][3 * 4 + jc][mC] + bs2f((short)(gw[3] >> sh));
            q0 = fminf(fmaxf(q0, -30.f), 30.f);
            q1 = fminf(fmaxf(q1, -30.f), 30.f);
            q2 = fminf(fmaxf(q2, -30.f), 30.f);
            q3 = fminf(fmaxf(q3, -30.f), 30.f);
            const float ig = 1.f / (1.f + __expf(-q0));
            const float fg = 1.f / (1.f + __expf(-q1));
            const float te = __expf(2.f * q2);
            const float gg = (te - 1.f) / (te + 1.f);
            const float og = 1.f / (1.f + __expf(-q3));
            float cs = (c == 0) ? cs0 : cs1;
            cs = fg * cs + ig * gg;
            const float csc = fminf(fmaxf(cs, -15.f), 15.f);
            const float t2 = __expf(2.f * csc);
            const float th = (t2 - 1.f) / (t2 + 1.f);
            const float h = og * th;
            if (c == 0) { cs0 = cs; hv0 = h; } else { cs1 = cs; hv1 = h; }
        }

        // ---- writes: dout (fp32, plain) + h publish (relaxed agent store) ----
        {
            float2 ho; ho.x = hv0; ho.y = hv1;
            *(float2*)(dout + ((size_t)mC * TT + t_x) * (2 * HH) + (size_t)dir * HH + j0 + jjA) = ho;

            bf16 hb0 = f2bf(hv0), hb1 = f2bf(hv1);
            unsigned pk = (unsigned)*(unsigned short*)&hb0 |
                          ((unsigned)*(unsigned short*)&hb1 << 16);
            unsigned* hp = (unsigned*)(hsl + (size_t)((s + 1) & 1) * BH + (size_t)mC * HH + j0 + jjA);
            __hip_atomic_store(hp, pk, __ATOMIC_RELAXED, __HIP_MEMORY_SCOPE_AGENT);

            if (s == TT - 1) {
                const size_t hn_off = (size_t)BB * TT * 2 * HH;
                float2 co; co.x = cs0; co.y = cs1;
                *(float2*)(dout + hn_off + (size_t)dir * BH + (size_t)mC * HH + j0 + jjA) = ho;
                *(float2*)(dout + hn_off + 2 * (size_t)BH + (size_t)dir * BH + (size_t)mC * HH + j0 + jjA) = co;
            }
        }

        // ---- barrier + restage (skip after last step) ----
        if (s < TT - 1) {
            asm volatile("s_waitcnt vmcnt(0)" ::: "memory");  // h publish complete
            __syncthreads();                                   // whole WG done
            if (tid == 0)
                __hip_atomic_fetch_add(barsd + (wgl & 3) * 64, 1u,
                                       __ATOMIC_RELAXED, __HIP_MEMORY_SCOPE_AGENT);
            // prefetch next gx while spinning
            const int t_n = dir ? (TT - 2 - s) : (s + 1);
            unsigned gwn[4];
#pragma unroll
            for (int gg = 0; gg < 4; ++gg)
                gwn[gg] = gxw[((size_t)(t_n * 4 + gg) * 128 + cg) * 64 + l];

            if (wv == 0 && l < 4) {
                const unsigned tgt = (unsigned)(WGD / 4) * (unsigned)(s + 1);
                while (__hip_atomic_load(barsd + l * 64,
                                         __ATOMIC_RELAXED, __HIP_MEMORY_SCOPE_AGENT) < tgt) {
                    __builtin_amdgcn_s_sleep(1);
                }
            }
            if (wv == 0)
                asm volatile("buffer_inv sc1" ::: "memory");   // drop stale L1/L2 h lines
            __syncthreads();

            // cooperative stage of h slot (s+1)&1 : 32 KB, plain dwordx4 loads
            const uint4* src = (const uint4*)(hsl + (size_t)((s + 1) & 1) * BH);
#pragma unroll
            for (int q = 0; q < 8; ++q) {
                const int f16 = q * 256 + tid;       // 16B-chunk index, 2048 total
                const uint4 v = src[f16];
                const int e = f16 * 8;               // element index
                *(uint4*)&h_s[e >> 9][e & 511] = v;
            }
            __syncthreads();
#pragma unroll
            for (int gg = 0; gg < 4; ++gg) gw[gg] = gwn[gg];
        }
    }
}

// ---------------------------------------------------------------------------
extern "C" void kernel_launch(void* const* d_in, const int* in_sizes, int n_in,
                              void* d_out, int out_size, void* d_ws, size_t ws_size,
                              hipStream_t stream)
{
    (void)in_sizes; (void)n_in; (void)out_size;
    const float* x     = (const float*)d_in[0];
    const float* h0    = (const float*)d_in[1];
    const float* c0    = (const float*)d_in[2];
    const float* wih_f = (const float*)d_in[3];
    const float* whh_f = (const float*)d_in[4];
    const float* bih_f = (const float*)d_in[5];
    const float* bhh_f = (const float*)d_in[6];
    const float* wih_r = (const float*)d_in[7];
    const float* whh_r = (const float*)d_in[8];
    const float* bih_r = (const float*)d_in[9];
    const float* bhh_r = (const float*)d_in[10];
    float* out = (float*)d_out;

    const size_t gx1 = GX1 * sizeof(bf16);                   // 64 MB per direction
    const size_t needA = 2 * gx1 + (size_t)4 * BH * sizeof(bf16) + 4096;
    char* ws = (char*)d_ws;

    if (ws_size >= needA) {
        // Plan A: both directions concurrently (64 4-wave WGs).
        bf16* gx = (bf16*)ws;
        bf16* h_buf = (bf16*)(ws + 2 * gx1);
        unsigned int* bars = (unsigned int*)(ws + 2 * gx1 + (size_t)4 * BH * sizeof(bf16));
        hipMemsetAsync(bars, 0, 2048, stream);
        dim3 g1(MM / 64, G4 / 128, 2);
        proj_mfma_kernel<<<g1, 256, 0, stream>>>(x, wih_f, wih_r, bih_f, bhh_f, bih_r, bhh_r, gx, 0);
        lstm_rec_kernel<<<dim3(2 * WGD), dim3(256), 0, stream>>>(
            gx, h0, c0, whh_f, whh_r, out, h_buf, bars, 0);
    } else {
        // Plan B: sequential per-direction, single 64 MB gx buffer reused.
        bf16* gx = (bf16*)ws;
        bf16* h_buf = (bf16*)(ws + gx1);
        unsigned int* bars = (unsigned int*)(ws + gx1 + (size_t)2 * BH * sizeof(bf16));
        for (int d = 0; d < 2; ++d) {
            hipMemsetAsync(bars, 0, 2048, stream);
            dim3 g1(MM / 64, G4 / 128, 1);
            proj_mfma_kernel<<<g1, 256, 0, stream>>>(x, wih_f, wih_r, bih_f, bhh_f, bih_r, bhh_r, gx, d);
            lstm_rec_kernel<<<dim3(WGD), dim3(256), 0, stream>>>(
                gx, h0, c0, whh_f, whh_r, out, h_buf, bars, d);
        }
    }
}

// Round 6
// 1891.753 us; speedup vs baseline: 8.8590x; 1.2117x over previous
//
#include <hip/hip_runtime.h>
#include <hip/hip_bf16.h>
#include <math.h>
#include <stdint.h>

#define BB 32
#define TT 512
#define II 512
#define HH 512
#define G4 (4 * HH)      // 2048
#define MM (TT * BB)     // 16384 rows of gx per direction
#define BH (BB * HH)     // 16384
#define WGD 32           // workgroups per direction in rec kernel (4 waves each)

typedef __hip_bfloat16 bf16;
typedef __attribute__((ext_vector_type(8))) short short8;   // 8 bf16 = 4 VGPRs
typedef __attribute__((ext_vector_type(4))) float f32x4;    // MFMA accumulator
typedef __attribute__((ext_vector_type(4))) unsigned u32x4; // for asm loads

__device__ __forceinline__ float bf2f(bf16 v) { return __bfloat162float(v); }
__device__ __forceinline__ bf16  f2bf(float v) { return __float2bfloat16(v); }
__device__ __forceinline__ short f2bs(float x) { bf16 v = f2bf(x); return *reinterpret_cast<short*>(&v); }
__device__ __forceinline__ float bs2f(short s) {
    unsigned u = ((unsigned)(unsigned short)s) << 16;
    return __uint_as_float(u);
}
__device__ __forceinline__ short8 pk8(float4 u, float4 v) {
    short8 t;
    t[0] = f2bs(u.x); t[1] = f2bs(u.y); t[2] = f2bs(u.z); t[3] = f2bs(u.w);
    t[4] = f2bs(v.x); t[5] = f2bs(v.y); t[6] = f2bs(v.z); t[7] = f2bs(v.w);
    return t;
}

// gx gate-planar swizzle: [dl][t][g][cg 0..127][b*4 + jj] bf16
#define GX1 ((size_t)TT * 4 * 128 * 128)   // elements per direction (= MM*G4)

// ---------------------------------------------------------------------------
// Phase 1: input projection GEMM via MFMA (bf16 in / fp32 acc). Unchanged.
// ---------------------------------------------------------------------------
__global__ __launch_bounds__(256) void proj_mfma_kernel(
    const float* __restrict__ x,
    const float* __restrict__ w_f, const float* __restrict__ w_r,
    const float* __restrict__ bi_f, const float* __restrict__ bh_f,
    const float* __restrict__ bi_r, const float* __restrict__ bh_r,
    bf16* __restrict__ gx, int dir0)
{
    const int dl = blockIdx.z, dir = dir0 + dl;
    const int m0 = blockIdx.x * 64;
    const int n0 = blockIdx.y * 128;
    const float* __restrict__ w  = dir ? w_r  : w_f;
    const float* __restrict__ bi = dir ? bi_r : bi_f;
    const float* __restrict__ bh = dir ? bh_r : bh_f;

    __shared__ __align__(16) char smem[17408];
    bf16 (*As)[40]  = (bf16(*)[40])smem;            // 64 x (32+8 pad)
    bf16 (*Bs)[40]  = (bf16(*)[40])(smem + 5120);   // 128 x (32+8 pad)
    bf16 (*Cs)[136] = (bf16(*)[136])smem;           // 64 x 136 (reuses smem)

    const int tid = threadIdx.x;
    const int wv = tid >> 6, l = tid & 63;
    const int nl = l & 15, ko = (l >> 4) * 8;

    const int a_r = tid >> 2, a_s = tid & 3;
    const float* a_src = x + ((size_t)((m0 + a_r) & 31) * TT + (size_t)((m0 + a_r) >> 5)) * II + a_s * 8;
    const int b_r = tid >> 1, b_h = tid & 1;
    const float* b_src = w + (size_t)(n0 + b_r) * II + b_h * 16;

    f32x4 acc[8];
#pragma unroll
    for (int j = 0; j < 8; ++j) acc[j] = (f32x4){0.f, 0.f, 0.f, 0.f};

    float bias[8];
#pragma unroll
    for (int j = 0; j < 8; ++j) {
        const int n = n0 + j * 16 + nl;
        bias[j] = bi[n] + bh[n];
    }

    for (int k0 = 0; k0 < II; k0 += 32) {
        const float4 av0 = *(const float4*)(a_src + k0);
        const float4 av1 = *(const float4*)(a_src + k0 + 4);
        const float4 bv0 = *(const float4*)(b_src + k0);
        const float4 bv1 = *(const float4*)(b_src + k0 + 4);
        const float4 bv2 = *(const float4*)(b_src + k0 + 8);
        const float4 bv3 = *(const float4*)(b_src + k0 + 12);
        __syncthreads();   // previous tile fully consumed
        *(short8*)&As[a_r][a_s * 8] = pk8(av0, av1);
        *(short8*)&Bs[b_r][b_h * 16]     = pk8(bv0, bv1);
        *(short8*)&Bs[b_r][b_h * 16 + 8] = pk8(bv2, bv3);
        __syncthreads();
        const short8 a = *(const short8*)&As[wv * 16 + nl][ko];
#pragma unroll
        for (int j = 0; j < 8; ++j) {
            const short8 b = *(const short8*)&Bs[j * 16 + nl][ko];
            acc[j] = __builtin_amdgcn_mfma_f32_16x16x32_bf16(a, b, acc[j], 0, 0, 0);
        }
    }

    __syncthreads();
    const int row0 = (l >> 4) * 4;
#pragma unroll
    for (int j = 0; j < 8; ++j)
#pragma unroll
        for (int r = 0; r < 4; ++r)
            Cs[wv * 16 + row0 + r][j * 16 + nl] = f2bf(acc[j][r] + bias[j]);
    __syncthreads();

    bf16* gxd = gx + (size_t)dl * GX1;
    const int g   = n0 >> 9;
    const int cgb = (n0 & 511) >> 2;
    const int t_base = blockIdx.x * 2;
#pragma unroll
    for (int i = 0; i < 4; ++i) {
        const int c = i * 256 + tid;
        const int tl = c >> 9, cgl = (c >> 4) & 31, u = c & 15;
        const int r0 = tl * 32 + 2 * u;
        const uint2 lo = *(const uint2*)&Cs[r0][cgl * 4];
        const uint2 hi = *(const uint2*)&Cs[r0 + 1][cgl * 4];
        uint4 ov; ov.x = lo.x; ov.y = lo.y; ov.z = hi.x; ov.w = hi.y;
        *(uint4*)(gxd + ((((size_t)(t_base + tl) * 4 + g) * 128 + cgb + cgl) * 128 + u * 8)) = ov;
    }
}

// ---------------------------------------------------------------------------
// Phase 2: MFMA recurrence. Round-6 changes:
//  - no buffer_inv: h restage uses per-load sc0 sc1 (bypass L1+L2, read L3)
//  - publish h FIRST, waitcnt only covers publish, arrive immediately;
//    dout stores + gx prefetch issued inside the spin window.
// ---------------------------------------------------------------------------
__global__ __launch_bounds__(256, 1) void lstm_rec_kernel(
    const bf16* __restrict__ gx,
    const float* __restrict__ h0, const float* __restrict__ c0,
    const float* __restrict__ whh_f, const float* __restrict__ whh_r,
    float* __restrict__ dout,
    bf16* __restrict__ h_buf,          // [ndir][2 slots][BH]
    unsigned int* __restrict__ bars,   // [ndir][4 counters x 64 uints]
    int dir0)
{
    const int dl  = blockIdx.x >> 5;
    const int wgl = blockIdx.x & 31;
    const int dir = dir0 + dl;
    const int tid = threadIdx.x;
    const int wv  = tid >> 6;            // wave 0..3
    const int l   = tid & 63;            // lane
    const int cg  = wgl * 4 + wv;        // col-group 0..127
    const int j0  = cg * 4;
    const float* __restrict__ whh = dir ? whh_r : whh_f;
    unsigned int* barsd = bars + (size_t)dl * 256;

    __shared__ __align__(16) bf16 h_s[32][520];   // staged h, +8 pad
    __shared__ __align__(16) float ex[4][16][36]; // per-wave gate exchange

    const int nl = l & 15;                // packed col index = gate*4 + jj
    const int g  = nl >> 2, jj = nl & 3;
    const int ko = (l >> 4) * 8;          // k-octet within a K=32 MFMA step

    // ---- B fragments (w_hh) resident in registers ----
    short8 bfrag[16];
    {
        const float* wr = whh + ((size_t)g * HH + (size_t)(j0 + jj)) * HH;
#pragma unroll
        for (int ks = 0; ks < 16; ++ks) {
            const float* p = wr + ks * 32 + ko;
            short8 t;
#pragma unroll
            for (int i = 0; i < 8; ++i) t[i] = f2bs(p[i]);
            bfrag[ks] = t;
        }
    }

    const int mC = l >> 1;
    const int jjA = (l & 1) * 2;

    float cs0, cs1;
    {
        const float* cp = c0 + (size_t)dir * BH + (size_t)mC * HH + j0 + jjA;
        cs0 = cp[0]; cs1 = cp[1];
    }

    bf16* hsl = h_buf + (size_t)dl * 2 * BH;
    const unsigned* gxw = (const unsigned*)(gx + (size_t)dl * GX1);

    // ---- stage initial h (fp32 h0 -> bf16 LDS) ----
    for (int q = 0; q < 64; ++q) {
        const int f = q * 256 + tid;
        h_s[f >> 9][f & 511] = f2bf(h0[(size_t)dir * BH + f]);
    }
    __syncthreads();

    // first gx fetch: 4 gate-planar dwords (2 cells each)
    unsigned gw[4];
    {
        const int t0 = dir ? (TT - 1) : 0;
#pragma unroll
        for (int gg = 0; gg < 4; ++gg)
            gw[gg] = gxw[((size_t)(t0 * 4 + gg) * 128 + cg) * 64 + l];
    }

#pragma unroll 1
    for (int s = 0; s < TT; ++s) {
        const int t_x = dir ? (TT - 1 - s) : s;

        // ---- MFMA: gates[32 x 16packed] = h . W^T, A from LDS ----
        f32x4 acc0 = {0.f, 0.f, 0.f, 0.f};
        f32x4 acc1 = {0.f, 0.f, 0.f, 0.f};
#pragma unroll
        for (int half = 0; half < 2; ++half) {
            short8 a0[8], a1[8];
#pragma unroll
            for (int k = 0; k < 8; ++k) {
                const int ks = half * 8 + k;
                a0[k] = *(const short8*)&h_s[nl][ks * 32 + ko];
                a1[k] = *(const short8*)&h_s[nl + 16][ks * 32 + ko];
            }
#pragma unroll
            for (int k = 0; k < 8; ++k) {
                acc0 = __builtin_amdgcn_mfma_f32_16x16x32_bf16(a0[k], bfrag[half * 8 + k], acc0, 0, 0, 0);
                acc1 = __builtin_amdgcn_mfma_f32_16x16x32_bf16(a1[k], bfrag[half * 8 + k], acc1, 0, 0, 0);
            }
        }

        // ---- exchange C-layout -> cell layout through per-wave LDS slice ----
        {
            const int row0 = (l >> 4) * 4;
            *(f32x4*)&ex[wv][nl][row0]      = acc0;
            *(f32x4*)&ex[wv][nl][16 + row0] = acc1;
        }

        float hv0, hv1;
#pragma unroll
        for (int c = 0; c < 2; ++c) {
            const int jc = jjA + c;
            const int sh = 16 * c;
            float q0 = ex[wv][0 * 4 + jc][mC] + bs2f((short)(gw[0] >> sh));
            float q1 = ex[wv][1 * 4 + jc][mC] + bs2f((short)(gw[1] >> sh));
            float q2 = ex[wv][2 * 4 + jc][mC] + bs2f((short)(gw[2] >> sh));
            float q3 = ex[wv][3 * 4 + jc][mC] + bs2f((short)(gw[3] >> sh));
            q0 = fminf(fmaxf(q0, -30.f), 30.f);
            q1 = fminf(fmaxf(q1, -30.f), 30.f);
            q2 = fminf(fmaxf(q2, -30.f), 30.f);
            q3 = fminf(fmaxf(q3, -30.f), 30.f);
            const float ig = 1.f / (1.f + __expf(-q0));
            const float fg = 1.f / (1.f + __expf(-q1));
            const float te = __expf(2.f * q2);
            const float gg = (te - 1.f) / (te + 1.f);
            const float og = 1.f / (1.f + __expf(-q3));
            float cs = (c == 0) ? cs0 : cs1;
            cs = fg * cs + ig * gg;
            const float csc = fminf(fmaxf(cs, -15.f), 15.f);
            const float t2 = __expf(2.f * csc);
            const float th = (t2 - 1.f) / (t2 + 1.f);
            const float h = og * th;
            if (c == 0) { cs0 = cs; hv0 = h; } else { cs1 = cs; hv1 = h; }
        }

        if (s < TT - 1) {
            // ---- publish h FIRST (relaxed agent store, write-through) ----
            {
                bf16 hb0 = f2bf(hv0), hb1 = f2bf(hv1);
                unsigned pk = (unsigned)*(unsigned short*)&hb0 |
                              ((unsigned)*(unsigned short*)&hb1 << 16);
                unsigned* hp = (unsigned*)(hsl + (size_t)((s + 1) & 1) * BH + (size_t)mC * HH + j0 + jjA);
                __hip_atomic_store(hp, pk, __ATOMIC_RELAXED, __HIP_MEMORY_SCOPE_AGENT);
            }
            asm volatile("s_waitcnt vmcnt(0)" ::: "memory");  // publish visible
            __syncthreads();                                   // whole WG published
            if (tid == 0)
                __hip_atomic_fetch_add(barsd + (wgl & 3) * 64, 1u,
                                       __ATOMIC_RELAXED, __HIP_MEMORY_SCOPE_AGENT);

            // ---- spin-window work: dout store + next gx prefetch ----
            {
                float2 ho; ho.x = hv0; ho.y = hv1;
                *(float2*)(dout + ((size_t)mC * TT + t_x) * (2 * HH) + (size_t)dir * HH + j0 + jjA) = ho;
            }
            const int t_n = dir ? (TT - 2 - s) : (s + 1);
            unsigned gwn[4];
#pragma unroll
            for (int gg = 0; gg < 4; ++gg)
                gwn[gg] = gxw[((size_t)(t_n * 4 + gg) * 128 + cg) * 64 + l];

            if (wv == 0 && l < 4) {
                const unsigned tgt = (unsigned)(WGD / 4) * (unsigned)(s + 1);
                while (__hip_atomic_load(barsd + l * 64,
                                         __ATOMIC_RELAXED, __HIP_MEMORY_SCOPE_AGENT) < tgt) {
                    __builtin_amdgcn_s_sleep(1);
                }
            }
            __syncthreads();

            // ---- restage h slot (s+1)&1: sc0 sc1 loads (L1/L2 bypass) ----
            {
                const u32x4* src = (const u32x4*)(hsl + (size_t)((s + 1) & 1) * BH);
                u32x4 vv[8];
#pragma unroll
                for (int q = 0; q < 8; ++q) {
                    const u32x4* p = src + (q * 256 + tid);
                    asm volatile("global_load_dwordx4 %0, %1, off sc0 sc1"
                                 : "=v"(vv[q]) : "v"(p));
                }
                asm volatile("s_waitcnt vmcnt(0)" ::: "memory");
#pragma unroll
                for (int q = 0; q < 8; ++q) {
                    const int e = (q * 256 + tid) * 8;
                    *(u32x4*)&h_s[e >> 9][e & 511] = vv[q];
                }
            }
            __syncthreads();
#pragma unroll
            for (int gg = 0; gg < 4; ++gg) gw[gg] = gwn[gg];
        } else {
            // ---- last step: dout + h_n/c_n ----
            float2 ho; ho.x = hv0; ho.y = hv1;
            *(float2*)(dout + ((size_t)mC * TT + t_x) * (2 * HH) + (size_t)dir * HH + j0 + jjA) = ho;
            const size_t hn_off = (size_t)BB * TT * 2 * HH;
            float2 co; co.x = cs0; co.y = cs1;
            *(float2*)(dout + hn_off + (size_t)dir * BH + (size_t)mC * HH + j0 + jjA) = ho;
            *(float2*)(dout + hn_off + 2 * (size_t)BH + (size_t)dir * BH + (size_t)mC * HH + j0 + jjA) = co;
        }
    }
}

// ---------------------------------------------------------------------------
extern "C" void kernel_launch(void* const* d_in, const int* in_sizes, int n_in,
                              void* d_out, int out_size, void* d_ws, size_t ws_size,
                              hipStream_t stream)
{
    (void)in_sizes; (void)n_in; (void)out_size;
    const float* x     = (const float*)d_in[0];
    const float* h0    = (const float*)d_in[1];
    const float* c0    = (const float*)d_in[2];
    const float* wih_f = (const float*)d_in[3];
    const float* whh_f = (const float*)d_in[4];
    const float* bih_f = (const float*)d_in[5];
    const float* bhh_f = (const float*)d_in[6];
    const float* wih_r = (const float*)d_in[7];
    const float* whh_r = (const float*)d_in[8];
    const float* bih_r = (const float*)d_in[9];
    const float* bhh_r = (const float*)d_in[10];
    float* out = (float*)d_out;

    const size_t gx1 = GX1 * sizeof(bf16);                   // 64 MB per direction
    const size_t needA = 2 * gx1 + (size_t)4 * BH * sizeof(bf16) + 4096;
    char* ws = (char*)d_ws;

    if (ws_size >= needA) {
        // Plan A: both directions concurrently (64 4-wave WGs).
        bf16* gx = (bf16*)ws;
        bf16* h_buf = (bf16*)(ws + 2 * gx1);
        unsigned int* bars = (unsigned int*)(ws + 2 * gx1 + (size_t)4 * BH * sizeof(bf16));
        hipMemsetAsync(bars, 0, 2048, stream);
        dim3 g1(MM / 64, G4 / 128, 2);
        proj_mfma_kernel<<<g1, 256, 0, stream>>>(x, wih_f, wih_r, bih_f, bhh_f, bih_r, bhh_r, gx, 0);
        lstm_rec_kernel<<<dim3(2 * WGD), dim3(256), 0, stream>>>(
            gx, h0, c0, whh_f, whh_r, out, h_buf, bars, 0);
    } else {
        // Plan B: sequential per-direction, single 64 MB gx buffer reused.
        bf16* gx = (bf16*)ws;
        bf16* h_buf = (bf16*)(ws + gx1);
        unsigned int* bars = (unsigned int*)(ws + gx1 + (size_t)2 * BH * sizeof(bf16));
        for (int d = 0; d < 2; ++d) {
            hipMemsetAsync(bars, 0, 2048, stream);
            dim3 g1(MM / 64, G4 / 128, 1);
            proj_mfma_kernel<<<g1, 256, 0, stream>>>(x, wih_f, wih_r, bih_f, bhh_f, bih_r, bhh_r, gx, d);
            lstm_rec_kernel<<<dim3(WGD), dim3(256), 0, stream>>>(
                gx, h0, c0, whh_f, whh_r, out, h_buf, bars, d);
        }
    }
}